// Round 9
// baseline (5263.173 us; speedup 1.0000x reference)
//
#include <hip/hip_runtime.h>

// SNN B=128, D0=512, T=512, dims 1024/1024/512, DECAY=0.5, THRESH=0.3
// Round 9: fuse the LIF temporal scan into the GEMM epilogue. M-order is
// batch-major per 128-step time slice (m = b*128 + tl), so a 128x128 tile is
// one batch x 128 timesteps x 128 neurons -> scan runs in-block from LDS.
// 4 slices x 3 layers = 12 GEMM launches; no I buffer, spikes stored bf16.
// K-loop core = round-8 gemm32 (proven absmax=0); states carried in global
// arrays between slice launches (stream order = dependency order).

typedef __bf16 bf16;
typedef __attribute__((ext_vector_type(8))) __bf16 bf16x8;
typedef __attribute__((ext_vector_type(16))) float f32x16;

#define B_   128
#define D0_  512
#define T_   512
#define TS_  128                 // timesteps per slice (= launch boundary)
#define N1_  1024
#define N2_  1024
#define N3_  512
#define MFMA32(a,b,c) __builtin_amdgcn_mfma_f32_32x32x16_bf16((a),(b),(c),0,0,0)

#define GL2LDS(g, l) __builtin_amdgcn_global_load_lds( \
    (const __attribute__((address_space(1))) void*)(g), \
    (__attribute__((address_space(3))) void*)(l), 16, 0, 0)

// ---------- setup ----------

// W [K][N] fp32 -> WTh/WTl [N][K] bf16 (transposed hi/lo split)
__global__ __launch_bounds__(256)
void split_w(const float* __restrict__ W, bf16* __restrict__ WTh, bf16* __restrict__ WTl,
             int K, int N)
{
    __shared__ float tile[32][33];
    const int k0 = blockIdx.x * 32, n0 = blockIdx.y * 32;
    const int tx = threadIdx.x & 31, ty = threadIdx.x >> 5;
#pragma unroll
    for (int r = 0; r < 4; ++r)
        tile[ty + r * 8][tx] = W[(size_t)(k0 + ty + r * 8) * N + n0 + tx];
    __syncthreads();
#pragma unroll
    for (int r = 0; r < 4; ++r) {
        int nl = ty + r * 8;
        float v = tile[tx][nl];
        bf16 h = (bf16)v;
        size_t o = (size_t)(n0 + nl) * K + k0 + tx;
        WTh[o] = h;
        WTl[o] = (bf16)(v - (float)h);
    }
}

// x [B][D0][T] fp32 -> Xh/Xl slice-major [s][b][tl][D0] bf16 (hi/lo)
__global__ __launch_bounds__(256)
void split_x(const float* __restrict__ in, bf16* __restrict__ Xh, bf16* __restrict__ Xl)
{
    __shared__ float tile[32][33];
    const int b = blockIdx.z, d0 = blockIdx.x * 32, t0 = blockIdx.y * 32;
    const int tx = threadIdx.x & 31, ty = threadIdx.x >> 5;
#pragma unroll
    for (int r = 0; r < 4; ++r)
        tile[ty + r * 8][tx] = in[((size_t)b * D0_ + d0 + ty + r * 8) * T_ + t0 + tx];
    __syncthreads();
    const int s = t0 >> 7;                       // 32-t tile lies in one slice
#pragma unroll
    for (int r = 0; r < 4; ++r) {
        int t  = t0 + ty + r * 8;
        int tl = t & (TS_ - 1);
        float v = tile[tx][ty + r * 8];
        bf16 h = (bf16)v;
        size_t o = (((size_t)s * B_ + b) * TS_ + tl) * D0_ + d0 + tx;
        Xh[o] = h;
        Xl[o] = (bf16)(v - (float)h);
    }
}

// ---------- fused GEMM + LIF scan ----------
// A (slice base): [b][tl][K] bf16 rows; WT: [N][K] bf16 hi/lo.
// Block = (b = blockIdx.x, n-tile = blockIdx.y): computes I for 128 t x 128 n,
// then runs the LIF recurrence over t in-block (4 column-quarters of 32).
// State arrays mem_st [B][N] f32, spk_st [B][N] bf16 carry across slices.
template<int K, bool SPLITA, bool WRITE_SPK>
__global__ __launch_bounds__(256)
void gemm_lif(const bf16* __restrict__ Ah, const bf16* __restrict__ Al,
              const bf16* __restrict__ WTh, const bf16* __restrict__ WTl,
              float* __restrict__ mem_st, bf16* __restrict__ spk_st,
              bf16* __restrict__ Sout,          // spike-train slice base or null
              float* __restrict__ outp,         // d_out on final slice of L2
              int N)
{
    constexpr int SMEM = SPLITA ? 32768 : 24576;
    __shared__ char smem[SMEM];
    bf16* sAh = (bf16*)smem;
    bf16* sAl = (bf16*)(smem + 8192);                       // SPLITA only
    bf16* sBh = (bf16*)(smem + (SPLITA ? 16384 : 8192));
    bf16* sBl = (bf16*)(smem + (SPLITA ? 24576 : 16384));

    const int tid = threadIdx.x, lane = tid & 63, w = tid >> 6;
    const int wm = w & 1, wn = w >> 1;
    const int l31 = lane & 31, kh = lane >> 5;
    const int b = blockIdx.x;
    const size_t mb = (size_t)b * 128;
    const int nb = blockIdx.y * 128;

    // staging: wave w -> tile rows [w*32, w*32+32), XOR-swizzled source chunk
    const int i4 = lane >> 2, c4 = lane & 3;
    const int csrc = c4 ^ ((i4 >> 1) & 3);
    const bf16* gA  = Ah + (mb + w * 32 + i4) * K + csrc * 8;
    const bf16* gAl = SPLITA ? (Al + (mb + w * 32 + i4) * K + csrc * 8) : nullptr;
    const bf16* gBh = WTh + (size_t)(nb + w * 32 + i4) * K + csrc * 8;
    const bf16* gBl = WTl + (size_t)(nb + w * 32 + i4) * K + csrc * 8;
    bf16* lA  = sAh + w * 32 * 32;
    bf16* lAl = sAl + w * 32 * 32;
    bf16* lBh = sBh + w * 32 * 32;
    bf16* lBl = sBl + w * 32 * 32;

    int rA[2], rB[2], swA[2], swB[2];
#pragma unroll
    for (int i = 0; i < 2; ++i) {
        rA[i] = wm * 64 + i * 32 + l31;
        rB[i] = wn * 64 + i * 32 + l31;
        swA[i] = (rA[i] >> 1) & 3;
        swB[i] = (rB[i] >> 1) & 3;
    }

    f32x16 acc[2][2] = {};

#pragma unroll 1
    for (int s = 0; s < K / 32; ++s) {
        const int go = s * 32;
        __syncthreads();
#pragma unroll
        for (int inst = 0; inst < 2; ++inst) {
            GL2LDS(gA + (size_t)inst * 16 * K + go, lA + inst * 16 * 32);
            if constexpr (SPLITA)
                GL2LDS(gAl + (size_t)inst * 16 * K + go, lAl + inst * 16 * 32);
            GL2LDS(gBh + (size_t)inst * 16 * K + go, lBh + inst * 16 * 32);
            GL2LDS(gBl + (size_t)inst * 16 * K + go, lBl + inst * 16 * 32);
        }
        __syncthreads();

        bf16x8 a[2][2], al2[2][2];
#pragma unroll
        for (int mi = 0; mi < 2; ++mi)
#pragma unroll
            for (int h = 0; h < 2; ++h) {
                const int off = rA[mi] * 32 + (((2 * h + kh) ^ swA[mi]) * 8);
                a[mi][h] = *(const bf16x8*)(sAh + off);
                if constexpr (SPLITA)
                    al2[mi][h] = *(const bf16x8*)(sAl + off);
            }
#pragma unroll
        for (int ni = 0; ni < 2; ++ni) {
#pragma unroll
            for (int h = 0; h < 2; ++h) {
                const int off = rB[ni] * 32 + (((2 * h + kh) ^ swB[ni]) * 8);
                bf16x8 bh = *(const bf16x8*)(sBh + off);
                bf16x8 bl = *(const bf16x8*)(sBl + off);
#pragma unroll
                for (int mi = 0; mi < 2; ++mi) {
                    acc[mi][ni] = MFMA32(a[mi][h], bh, acc[mi][ni]);
                    if constexpr (SPLITA)
                        acc[mi][ni] = MFMA32(al2[mi][h], bh, acc[mi][ni]);
                    acc[mi][ni] = MFMA32(a[mi][h], bl, acc[mi][ni]);
                }
            }
        }
    }

    // ---- epilogue: LIF scan over the 128 timesteps of this tile ----
    float* If = (float*)smem;               // [128 t][32 cols] f32, 16 KB
    bf16*  Sp = (bf16*)(smem + 16384);      // [128 t][32 cols] bf16, 8 KB

#pragma unroll 1
    for (int qn = 0; qn < 4; ++qn) {
        __syncthreads();                    // smem free (prev phase done)
        if (wn == (qn >> 1)) {              // the 2 waves holding these cols
            const int ni = qn & 1;
#pragma unroll
            for (int mi = 0; mi < 2; ++mi)
#pragma unroll
                for (int r = 0; r < 16; ++r) {
                    const int t = wm * 64 + mi * 32 + (r & 3) + 8 * (r >> 2) + 4 * kh;
                    If[t * 32 + l31] = acc[mi][ni][r];   // proven C/D mapping
                }
        }
        __syncthreads();
        if (tid < 32) {                     // one thread per column
            const int n = nb + qn * 32 + tid;
            const size_t st = (size_t)b * N + n;
            float m  = mem_st[st];
            float sp = (float)spk_st[st];
#pragma unroll 4
            for (int t = 0; t < TS_; ++t) {
                float v = If[t * 32 + tid];
                m  = m * 0.5f * (1.0f - sp) + v;
                sp = (m > 0.3f) ? 1.0f : 0.0f;
                if constexpr (WRITE_SPK) Sp[t * 32 + tid] = (bf16)sp;
            }
            mem_st[st] = m;
            spk_st[st] = (bf16)sp;
            if (outp) outp[st] = sp;        // final-slice L2: spike at t=511
        }
        if constexpr (WRITE_SPK) {
            __syncthreads();
            // coalesced spike-train store: Sout[b][t][nb+qn*32 .. +32]
            const int t = tid >> 1, hf = tid & 1;
            const uint4* src = (const uint4*)(Sp + t * 32 + hf * 16);
            uint4* dst = (uint4*)(Sout + ((size_t)b * TS_ + t) * N + nb + qn * 32 + hf * 16);
            dst[0] = src[0];
            dst[1] = src[1];
        }
    }
}

extern "C" void kernel_launch(void* const* d_in, const int* in_sizes, int n_in,
                              void* d_out, int out_size, void* d_ws, size_t ws_size,
                              hipStream_t stream)
{
    const float* x  = (const float*)d_in[0];
    const float* w0 = (const float*)d_in[1];
    const float* w1 = (const float*)d_in[2];
    const float* w2 = (const float*)d_in[3];
    float* out = (float*)d_out;

    char* p = (char*)d_ws;
    // LIF states (contiguous -> one memset)
    float* mem0  = (float*)p;  p += (size_t)B_ * N1_ * 4;
    bf16*  spst0 = (bf16*)p;   p += (size_t)B_ * N1_ * 2;
    float* mem1  = (float*)p;  p += (size_t)B_ * N2_ * 4;
    bf16*  spst1 = (bf16*)p;   p += (size_t)B_ * N2_ * 2;
    float* mem2  = (float*)p;  p += (size_t)B_ * N3_ * 4;
    bf16*  spst2 = (bf16*)p;   p += (size_t)B_ * N3_ * 2;
    size_t stateBytes = (size_t)(p - (char*)d_ws);
    // weight splits
    bf16* w0h = (bf16*)p;  p += (size_t)N1_ * D0_ * 2;
    bf16* w0l = (bf16*)p;  p += (size_t)N1_ * D0_ * 2;
    bf16* w1h = (bf16*)p;  p += (size_t)N2_ * N1_ * 2;
    bf16* w1l = (bf16*)p;  p += (size_t)N2_ * N1_ * 2;
    bf16* w2h = (bf16*)p;  p += (size_t)N3_ * N2_ * 2;
    bf16* w2l = (bf16*)p;  p += (size_t)N3_ * N2_ * 2;
    // full-T activation buffers, slice-major (total 412.1 MB <= proven ws >= 413.0 MB)
    bf16* Xh   = (bf16*)p; p += (size_t)T_ * B_ * D0_ * 2;   // 67 MB
    bf16* Xl   = (bf16*)p; p += (size_t)T_ * B_ * D0_ * 2;   // 67 MB
    bf16* spk0 = (bf16*)p; p += (size_t)T_ * B_ * N1_ * 2;   // 134 MB
    bf16* spk1 = (bf16*)p; p += (size_t)T_ * B_ * N2_ * 2;   // 134 MB

    hipMemsetAsync(d_ws, 0, stateBytes, stream);
    split_w<<<dim3(D0_/32, N1_/32), 256, 0, stream>>>(w0, w0h, w0l, D0_, N1_);
    split_w<<<dim3(N1_/32, N2_/32), 256, 0, stream>>>(w1, w1h, w1l, N1_, N2_);
    split_w<<<dim3(N2_/32, N3_/32), 256, 0, stream>>>(w2, w2h, w2l, N2_, N3_);
    split_x<<<dim3(D0_/32, T_/32, B_), 256, 0, stream>>>(x, Xh, Xl);

    for (int s = 0; s < T_ / TS_; ++s) {
        const size_t a0 = (size_t)s * B_ * TS_;
        // L0: I0 = X@w0 (3-term split) + LIF -> spk0 train
        gemm_lif<D0_, true, true><<<dim3(B_, N1_/128), 256, 0, stream>>>(
            Xh + a0 * D0_, Xl + a0 * D0_, w0h, w0l,
            mem0, spst0, spk0 + a0 * N1_, nullptr, N1_);
        // L1: I1 = spk0@w1 + LIF -> spk1 train
        gemm_lif<N1_, false, true><<<dim3(B_, N2_/128), 256, 0, stream>>>(
            spk0 + a0 * N1_, nullptr, w1h, w1l,
            mem1, spst1, spk1 + a0 * N2_, nullptr, N2_);
        // L2: I2 = spk1@w2 + LIF; final slice writes d_out spikes
        gemm_lif<N2_, false, false><<<dim3(B_, N3_/128), 256, 0, stream>>>(
            spk1 + a0 * N2_, nullptr, w2h, w2l,
            mem2, spst2, nullptr, (s == T_/TS_ - 1) ? out : nullptr, N3_);
    }
}

// Round 10
// 1066.613 us; speedup vs baseline: 4.9345x; 4.9345x over previous
//
#include <hip/hip_runtime.h>

// SNN B=128, D0=512, T=512, dims 1024/1024/512, DECAY=0.5, THRESH=0.3
// Round 10: round-9 fused GEMM+LIF with the epilogue spill bug fixed.
// Root cause of r9's 5.3 ms: `#pragma unroll 1` on the phase loop made
// acc[mi][ni] dynamically indexed -> 64 acc VGPRs spilled to scratch ->
// 2 GB/dispatch of spill writes re-circulated every K-iteration.
// Fix: fully unroll the 4 phases (static acc indexing). Nothing else changed.

typedef __bf16 bf16;
typedef __attribute__((ext_vector_type(8))) __bf16 bf16x8;
typedef __attribute__((ext_vector_type(16))) float f32x16;

#define B_   128
#define D0_  512
#define T_   512
#define TS_  128                 // timesteps per slice (= launch boundary)
#define N1_  1024
#define N2_  1024
#define N3_  512
#define MFMA32(a,b,c) __builtin_amdgcn_mfma_f32_32x32x16_bf16((a),(b),(c),0,0,0)

#define GL2LDS(g, l) __builtin_amdgcn_global_load_lds( \
    (const __attribute__((address_space(1))) void*)(g), \
    (__attribute__((address_space(3))) void*)(l), 16, 0, 0)

// ---------- setup ----------

// W [K][N] fp32 -> WTh/WTl [N][K] bf16 (transposed hi/lo split)
__global__ __launch_bounds__(256)
void split_w(const float* __restrict__ W, bf16* __restrict__ WTh, bf16* __restrict__ WTl,
             int K, int N)
{
    __shared__ float tile[32][33];
    const int k0 = blockIdx.x * 32, n0 = blockIdx.y * 32;
    const int tx = threadIdx.x & 31, ty = threadIdx.x >> 5;
#pragma unroll
    for (int r = 0; r < 4; ++r)
        tile[ty + r * 8][tx] = W[(size_t)(k0 + ty + r * 8) * N + n0 + tx];
    __syncthreads();
#pragma unroll
    for (int r = 0; r < 4; ++r) {
        int nl = ty + r * 8;
        float v = tile[tx][nl];
        bf16 h = (bf16)v;
        size_t o = (size_t)(n0 + nl) * K + k0 + tx;
        WTh[o] = h;
        WTl[o] = (bf16)(v - (float)h);
    }
}

// x [B][D0][T] fp32 -> Xh/Xl slice-major [s][b][tl][D0] bf16 (hi/lo)
__global__ __launch_bounds__(256)
void split_x(const float* __restrict__ in, bf16* __restrict__ Xh, bf16* __restrict__ Xl)
{
    __shared__ float tile[32][33];
    const int b = blockIdx.z, d0 = blockIdx.x * 32, t0 = blockIdx.y * 32;
    const int tx = threadIdx.x & 31, ty = threadIdx.x >> 5;
#pragma unroll
    for (int r = 0; r < 4; ++r)
        tile[ty + r * 8][tx] = in[((size_t)b * D0_ + d0 + ty + r * 8) * T_ + t0 + tx];
    __syncthreads();
    const int s = t0 >> 7;                       // 32-t tile lies in one slice
#pragma unroll
    for (int r = 0; r < 4; ++r) {
        int t  = t0 + ty + r * 8;
        int tl = t & (TS_ - 1);
        float v = tile[tx][ty + r * 8];
        bf16 h = (bf16)v;
        size_t o = (((size_t)s * B_ + b) * TS_ + tl) * D0_ + d0 + tx;
        Xh[o] = h;
        Xl[o] = (bf16)(v - (float)h);
    }
}

// ---------- fused GEMM + LIF scan ----------
// A (slice base): [b][tl][K] bf16 rows; WT: [N][K] bf16 hi/lo.
// Block (b, n-tile): computes I for 128 t x 128 n, then runs the LIF scan
// over t in-block, 4 column-quarters of 32 (fully unrolled, static acc idx).
template<int K, bool SPLITA, bool WRITE_SPK>
__global__ __launch_bounds__(256)
void gemm_lif(const bf16* __restrict__ Ah, const bf16* __restrict__ Al,
              const bf16* __restrict__ WTh, const bf16* __restrict__ WTl,
              float* __restrict__ mem_st, bf16* __restrict__ spk_st,
              bf16* __restrict__ Sout,          // spike-train slice base or null
              float* __restrict__ outp,         // d_out on final slice of L2
              int N)
{
    constexpr int SMEM = SPLITA ? 32768 : 24576;
    __shared__ char smem[SMEM];
    bf16* sAh = (bf16*)smem;
    bf16* sAl = (bf16*)(smem + 8192);                       // SPLITA only
    bf16* sBh = (bf16*)(smem + (SPLITA ? 16384 : 8192));
    bf16* sBl = (bf16*)(smem + (SPLITA ? 24576 : 16384));

    const int tid = threadIdx.x, lane = tid & 63, w = tid >> 6;
    const int wm = w & 1, wn = w >> 1;
    const int l31 = lane & 31, kh = lane >> 5;
    const int b = blockIdx.x;
    const size_t mb = (size_t)b * 128;
    const int nb = blockIdx.y * 128;

    // staging: wave w -> tile rows [w*32, w*32+32), XOR-swizzled source chunk
    const int i4 = lane >> 2, c4 = lane & 3;
    const int csrc = c4 ^ ((i4 >> 1) & 3);
    const bf16* gA  = Ah + (mb + w * 32 + i4) * K + csrc * 8;
    const bf16* gAl = SPLITA ? (Al + (mb + w * 32 + i4) * K + csrc * 8) : nullptr;
    const bf16* gBh = WTh + (size_t)(nb + w * 32 + i4) * K + csrc * 8;
    const bf16* gBl = WTl + (size_t)(nb + w * 32 + i4) * K + csrc * 8;
    bf16* lA  = sAh + w * 32 * 32;
    bf16* lAl = sAl + w * 32 * 32;
    bf16* lBh = sBh + w * 32 * 32;
    bf16* lBl = sBl + w * 32 * 32;

    int rA[2], rB[2], swA[2], swB[2];
#pragma unroll
    for (int i = 0; i < 2; ++i) {
        rA[i] = wm * 64 + i * 32 + l31;
        rB[i] = wn * 64 + i * 32 + l31;
        swA[i] = (rA[i] >> 1) & 3;
        swB[i] = (rB[i] >> 1) & 3;
    }

    f32x16 acc[2][2] = {};

#pragma unroll 1
    for (int s = 0; s < K / 32; ++s) {
        const int go = s * 32;
        __syncthreads();
#pragma unroll
        for (int inst = 0; inst < 2; ++inst) {
            GL2LDS(gA + (size_t)inst * 16 * K + go, lA + inst * 16 * 32);
            if constexpr (SPLITA)
                GL2LDS(gAl + (size_t)inst * 16 * K + go, lAl + inst * 16 * 32);
            GL2LDS(gBh + (size_t)inst * 16 * K + go, lBh + inst * 16 * 32);
            GL2LDS(gBl + (size_t)inst * 16 * K + go, lBl + inst * 16 * 32);
        }
        __syncthreads();

        bf16x8 a[2][2], al2[2][2];
#pragma unroll
        for (int mi = 0; mi < 2; ++mi)
#pragma unroll
            for (int h = 0; h < 2; ++h) {
                const int off = rA[mi] * 32 + (((2 * h + kh) ^ swA[mi]) * 8);
                a[mi][h] = *(const bf16x8*)(sAh + off);
                if constexpr (SPLITA)
                    al2[mi][h] = *(const bf16x8*)(sAl + off);
            }
#pragma unroll
        for (int ni = 0; ni < 2; ++ni) {
#pragma unroll
            for (int h = 0; h < 2; ++h) {
                const int off = rB[ni] * 32 + (((2 * h + kh) ^ swB[ni]) * 8);
                bf16x8 bh = *(const bf16x8*)(sBh + off);
                bf16x8 bl = *(const bf16x8*)(sBl + off);
#pragma unroll
                for (int mi = 0; mi < 2; ++mi) {
                    acc[mi][ni] = MFMA32(a[mi][h], bh, acc[mi][ni]);
                    if constexpr (SPLITA)
                        acc[mi][ni] = MFMA32(al2[mi][h], bh, acc[mi][ni]);
                    acc[mi][ni] = MFMA32(a[mi][h], bl, acc[mi][ni]);
                }
            }
        }
    }

    // ---- epilogue: LIF scan over the 128 timesteps of this tile ----
    // FULLY UNROLLED phases: acc indexed statically (r9's unroll-1 spilled).
    float* If = (float*)smem;               // [128 t][32 cols] f32, 16 KB
    bf16*  Sp = (bf16*)(smem + 16384);      // [128 t][32 cols] bf16, 8 KB

#pragma unroll
    for (int qn = 0; qn < 4; ++qn) {
        const int ni = qn & 1;              // compile-time after unroll
        __syncthreads();                    // smem free (prev phase done)
        if (wn == (qn >> 1)) {              // the 2 waves holding these cols
#pragma unroll
            for (int mi = 0; mi < 2; ++mi)
#pragma unroll
                for (int r = 0; r < 16; ++r) {
                    const int t = wm * 64 + mi * 32 + (r & 3) + 8 * (r >> 2) + 4 * kh;
                    If[t * 32 + l31] = acc[mi][ni][r];   // proven C/D mapping
                }
        }
        __syncthreads();
        if (tid < 32) {                     // one thread per column
            const int n = nb + qn * 32 + tid;
            const size_t st = (size_t)b * N + n;
            float m  = mem_st[st];
            float sp = (float)spk_st[st];
#pragma unroll 4
            for (int t = 0; t < TS_; ++t) {
                float v = If[t * 32 + tid];
                m  = m * 0.5f * (1.0f - sp) + v;
                sp = (m > 0.3f) ? 1.0f : 0.0f;
                if constexpr (WRITE_SPK) Sp[t * 32 + tid] = (bf16)sp;
            }
            mem_st[st] = m;
            spk_st[st] = (bf16)sp;
            if (outp) outp[st] = sp;        // final-slice L2: spike at t=511
        }
        if constexpr (WRITE_SPK) {
            __syncthreads();
            // coalesced spike-train store: Sout[b][t][nb+qn*32 .. +32]
            const int t = tid >> 1, hf = tid & 1;
            const uint4* src = (const uint4*)(Sp + t * 32 + hf * 16);
            uint4* dst = (uint4*)(Sout + ((size_t)b * TS_ + t) * N + nb + qn * 32 + hf * 16);
            dst[0] = src[0];
            dst[1] = src[1];
        }
    }
}

extern "C" void kernel_launch(void* const* d_in, const int* in_sizes, int n_in,
                              void* d_out, int out_size, void* d_ws, size_t ws_size,
                              hipStream_t stream)
{
    const float* x  = (const float*)d_in[0];
    const float* w0 = (const float*)d_in[1];
    const float* w1 = (const float*)d_in[2];
    const float* w2 = (const float*)d_in[3];
    float* out = (float*)d_out;

    char* p = (char*)d_ws;
    // LIF states (contiguous -> one memset)
    float* mem0  = (float*)p;  p += (size_t)B_ * N1_ * 4;
    bf16*  spst0 = (bf16*)p;   p += (size_t)B_ * N1_ * 2;
    float* mem1  = (float*)p;  p += (size_t)B_ * N2_ * 4;
    bf16*  spst1 = (bf16*)p;   p += (size_t)B_ * N2_ * 2;
    float* mem2  = (float*)p;  p += (size_t)B_ * N3_ * 4;
    bf16*  spst2 = (bf16*)p;   p += (size_t)B_ * N3_ * 2;
    size_t stateBytes = (size_t)(p - (char*)d_ws);
    // weight splits
    bf16* w0h = (bf16*)p;  p += (size_t)N1_ * D0_ * 2;
    bf16* w0l = (bf16*)p;  p += (size_t)N1_ * D0_ * 2;
    bf16* w1h = (bf16*)p;  p += (size_t)N2_ * N1_ * 2;
    bf16* w1l = (bf16*)p;  p += (size_t)N2_ * N1_ * 2;
    bf16* w2h = (bf16*)p;  p += (size_t)N3_ * N2_ * 2;
    bf16* w2l = (bf16*)p;  p += (size_t)N3_ * N2_ * 2;
    // full-T activation buffers, slice-major (total 412.1 MB <= proven ws >= 413.0 MB)
    bf16* Xh   = (bf16*)p; p += (size_t)T_ * B_ * D0_ * 2;   // 67 MB
    bf16* Xl   = (bf16*)p; p += (size_t)T_ * B_ * D0_ * 2;   // 67 MB
    bf16* spk0 = (bf16*)p; p += (size_t)T_ * B_ * N1_ * 2;   // 134 MB
    bf16* spk1 = (bf16*)p; p += (size_t)T_ * B_ * N2_ * 2;   // 134 MB

    hipMemsetAsync(d_ws, 0, stateBytes, stream);
    split_w<<<dim3(D0_/32, N1_/32), 256, 0, stream>>>(w0, w0h, w0l, D0_, N1_);
    split_w<<<dim3(N1_/32, N2_/32), 256, 0, stream>>>(w1, w1h, w1l, N1_, N2_);
    split_w<<<dim3(N2_/32, N3_/32), 256, 0, stream>>>(w2, w2h, w2l, N2_, N3_);
    split_x<<<dim3(D0_/32, T_/32, B_), 256, 0, stream>>>(x, Xh, Xl);

    for (int s = 0; s < T_ / TS_; ++s) {
        const size_t a0 = (size_t)s * B_ * TS_;
        // L0: I0 = X@w0 (3-term split) + LIF -> spk0 train
        gemm_lif<D0_, true, true><<<dim3(B_, N1_/128), 256, 0, stream>>>(
            Xh + a0 * D0_, Xl + a0 * D0_, w0h, w0l,
            mem0, spst0, spk0 + a0 * N1_, nullptr, N1_);
        // L1: I1 = spk0@w1 + LIF -> spk1 train
        gemm_lif<N1_, false, true><<<dim3(B_, N2_/128), 256, 0, stream>>>(
            spk0 + a0 * N1_, nullptr, w1h, w1l,
            mem1, spst1, spk1 + a0 * N2_, nullptr, N2_);
        // L2: I2 = spk1@w2 + LIF; final slice writes d_out spikes
        gemm_lif<N2_, false, false><<<dim3(B_, N3_/128), 256, 0, stream>>>(
            spk1 + a0 * N2_, nullptr, w2h, w2l,
            mem2, spst2, nullptr, (s == T_/TS_ - 1) ? out : nullptr, N3_);
    }
}

// Round 11
// 1040.759 us; speedup vs baseline: 5.0571x; 1.0248x over previous
//
#include <hip/hip_runtime.h>

// SNN B=128, D0=512, T=512, dims 1024/1024/512, DECAY=0.5, THRESH=0.3
// Round 11: one launch per layer (block loops all 4 time slices; LIF carry in
// registers), 2-phase parallel epilogue scan (128 threads, bit-packed spikes),
// 32 KB LDS -> 5 blocks/CU. GEMM K-loop core identical to r8/r10 (absmax=0).

typedef __bf16 bf16;
typedef __attribute__((ext_vector_type(8))) __bf16 bf16x8;
typedef __attribute__((ext_vector_type(16))) float f32x16;
typedef unsigned long long u64;

#define B_   128
#define D0_  512
#define T_   512
#define TS_  128
#define N1_  1024
#define N2_  1024
#define N3_  512
#define MFMA32(a,b,c) __builtin_amdgcn_mfma_f32_32x32x16_bf16((a),(b),(c),0,0,0)

#define GL2LDS(g, l) __builtin_amdgcn_global_load_lds( \
    (const __attribute__((address_space(1))) void*)(g), \
    (__attribute__((address_space(3))) void*)(l), 16, 0, 0)

// ---------- setup ----------

__global__ __launch_bounds__(256)
void split_w(const float* __restrict__ W, bf16* __restrict__ WTh, bf16* __restrict__ WTl,
             int K, int N)
{
    __shared__ float tile[32][33];
    const int k0 = blockIdx.x * 32, n0 = blockIdx.y * 32;
    const int tx = threadIdx.x & 31, ty = threadIdx.x >> 5;
#pragma unroll
    for (int r = 0; r < 4; ++r)
        tile[ty + r * 8][tx] = W[(size_t)(k0 + ty + r * 8) * N + n0 + tx];
    __syncthreads();
#pragma unroll
    for (int r = 0; r < 4; ++r) {
        int nl = ty + r * 8;
        float v = tile[tx][nl];
        bf16 h = (bf16)v;
        size_t o = (size_t)(n0 + nl) * K + k0 + tx;
        WTh[o] = h;
        WTl[o] = (bf16)(v - (float)h);
    }
}

// x [B][D0][T] fp32 -> Xh/Xl slice-major [s][b][tl][D0] bf16 (hi/lo)
__global__ __launch_bounds__(256)
void split_x(const float* __restrict__ in, bf16* __restrict__ Xh, bf16* __restrict__ Xl)
{
    __shared__ float tile[32][33];
    const int b = blockIdx.z, d0 = blockIdx.x * 32, t0 = blockIdx.y * 32;
    const int tx = threadIdx.x & 31, ty = threadIdx.x >> 5;
#pragma unroll
    for (int r = 0; r < 4; ++r)
        tile[ty + r * 8][tx] = in[((size_t)b * D0_ + d0 + ty + r * 8) * T_ + t0 + tx];
    __syncthreads();
    const int s = t0 >> 7;
#pragma unroll
    for (int r = 0; r < 4; ++r) {
        int t  = t0 + ty + r * 8;
        int tl = t & (TS_ - 1);
        float v = tile[tx][ty + r * 8];
        bf16 h = (bf16)v;
        size_t o = (((size_t)s * B_ + b) * TS_ + tl) * D0_ + d0 + tx;
        Xh[o] = h;
        Xl[o] = (bf16)(v - (float)h);
    }
}

// ---------- one whole SNN layer: 4 slices, fused GEMM + LIF ----------
// A: slice-major [s][b][tl][K] bf16 (+ Al if SPLITA). WT: [N][K] bf16 hi/lo.
// Block (b, ntile): loops slices; per slice: 128x128 GEMM then in-block LIF.
// Carry (m, spk) per column lives in scan-thread registers across slices.
template<int K, bool SPLITA, bool WRITE_SPK>
__global__ __launch_bounds__(256)
void snn_layer(const bf16* __restrict__ Ah, const bf16* __restrict__ Al,
               const bf16* __restrict__ WTh, const bf16* __restrict__ WTl,
               bf16* __restrict__ Sout,     // spike train [s][b][tl][N] or null
               float* __restrict__ outp,    // d_out (L2 only)
               int N)
{
    __shared__ char smem[32768];
    bf16* sAh = (bf16*)smem;
    bf16* sAl = (bf16*)(smem + 8192);                      // SPLITA only
    bf16* sBh = (bf16*)(smem + (SPLITA ? 16384 : 8192));
    bf16* sBl = (bf16*)(smem + (SPLITA ? 24576 : 16384));
    float* If = (float*)smem;                              // overlay [2][64][64] f32

    const int tid = threadIdx.x, lane = tid & 63, w = tid >> 6;
    const int wm = w & 1, wn = w >> 1;
    const int l31 = lane & 31, kh = lane >> 5;
    const int b = blockIdx.x;
    const int nb = blockIdx.y * 128;

    const int i4 = lane >> 2, c4 = lane & 3;
    const int csrc = c4 ^ ((i4 >> 1) & 3);
    const bf16* gBh = WTh + (size_t)(nb + w * 32 + i4) * K + csrc * 8;
    const bf16* gBl = WTl + (size_t)(nb + w * 32 + i4) * K + csrc * 8;
    bf16* lA  = sAh + w * 32 * 32;
    bf16* lAl = sAl + w * 32 * 32;
    bf16* lBh = sBh + w * 32 * 32;
    bf16* lBl = sBl + w * 32 * 32;

    int rA[2], rB[2], swA[2], swB[2];
#pragma unroll
    for (int i = 0; i < 2; ++i) {
        rA[i] = wm * 64 + i * 32 + l31;
        rB[i] = wn * 64 + i * 32 + l31;
        swA[i] = (rA[i] >> 1) & 3;
        swB[i] = (rB[i] >> 1) & 3;
    }

    // LIF carry (valid for tid < 128; column = nb + tid)
    float cm = 0.f, cs = 0.f;
    const int scol = tid & 63;
    float* Ifb = If + (tid >> 6) * 4096;

#pragma unroll 1
    for (int s = 0; s < T_ / TS_; ++s) {
        const size_t arow = ((size_t)s * B_ + b) * TS_;
        const bf16* gA  = Ah + (arow + w * 32 + i4) * K + csrc * 8;
        const bf16* gAl = SPLITA ? (Al + (arow + w * 32 + i4) * K + csrc * 8) : nullptr;

        f32x16 acc[2][2] = {};

#pragma unroll 1
        for (int ks = 0; ks < K / 32; ++ks) {
            const int go = ks * 32;
            __syncthreads();
#pragma unroll
            for (int inst = 0; inst < 2; ++inst) {
                GL2LDS(gA + (size_t)inst * 16 * K + go, lA + inst * 16 * 32);
                if constexpr (SPLITA)
                    GL2LDS(gAl + (size_t)inst * 16 * K + go, lAl + inst * 16 * 32);
                GL2LDS(gBh + (size_t)inst * 16 * K + go, lBh + inst * 16 * 32);
                GL2LDS(gBl + (size_t)inst * 16 * K + go, lBl + inst * 16 * 32);
            }
            __syncthreads();

            bf16x8 a[2][2], al2[2][2];
#pragma unroll
            for (int mi = 0; mi < 2; ++mi)
#pragma unroll
                for (int h = 0; h < 2; ++h) {
                    const int off = rA[mi] * 32 + (((2 * h + kh) ^ swA[mi]) * 8);
                    a[mi][h] = *(const bf16x8*)(sAh + off);
                    if constexpr (SPLITA)
                        al2[mi][h] = *(const bf16x8*)(sAl + off);
                }
#pragma unroll
            for (int ni = 0; ni < 2; ++ni) {
#pragma unroll
                for (int h = 0; h < 2; ++h) {
                    const int off = rB[ni] * 32 + (((2 * h + kh) ^ swB[ni]) * 8);
                    bf16x8 bh = *(const bf16x8*)(sBh + off);
                    bf16x8 bl = *(const bf16x8*)(sBl + off);
#pragma unroll
                    for (int mi = 0; mi < 2; ++mi) {
                        acc[mi][ni] = MFMA32(a[mi][h], bh, acc[mi][ni]);
                        if constexpr (SPLITA)
                            acc[mi][ni] = MFMA32(al2[mi][h], bh, acc[mi][ni]);
                        acc[mi][ni] = MFMA32(a[mi][h], bl, acc[mi][ni]);
                    }
                }
            }
        }

        // ---- epilogue: 2-phase parallel LIF scan (t-halves by wm) ----
        u64 blo = 0, bhi = 0;
        __syncthreads();
        if (wm == 0) {                       // dump t 0..63 (static acc idx)
#pragma unroll
            for (int ni = 0; ni < 2; ++ni)
#pragma unroll
                for (int mi = 0; mi < 2; ++mi)
#pragma unroll
                    for (int r = 0; r < 16; ++r) {
                        const int tt = mi * 32 + (r & 3) + 8 * (r >> 2) + 4 * kh;
                        If[wn * 4096 + tt * 64 + ni * 32 + l31] = acc[mi][ni][r];
                    }
        }
        __syncthreads();
        if (tid < 128) {                     // scan t 0..63, one col/thread
            float m = cm, sp = cs;
#pragma unroll 4
            for (int tt = 0; tt < 64; ++tt) {
                m  = m * 0.5f * (1.0f - sp) + Ifb[tt * 64 + scol];
                sp = (m > 0.3f) ? 1.0f : 0.0f;
                blo |= (u64)(m > 0.3f) << tt;
            }
            cm = m; cs = sp;
        }
        __syncthreads();
        if (wm == 1) {                       // dump t 64..127
#pragma unroll
            for (int ni = 0; ni < 2; ++ni)
#pragma unroll
                for (int mi = 0; mi < 2; ++mi)
#pragma unroll
                    for (int r = 0; r < 16; ++r) {
                        const int tt = mi * 32 + (r & 3) + 8 * (r >> 2) + 4 * kh;
                        If[wn * 4096 + tt * 64 + ni * 32 + l31] = acc[mi][ni][r];
                    }
        }
        __syncthreads();
        if (tid < 128) {                     // scan t 64..127
            float m = cm, sp = cs;
#pragma unroll 4
            for (int tt = 0; tt < 64; ++tt) {
                m  = m * 0.5f * (1.0f - sp) + Ifb[tt * 64 + scol];
                sp = (m > 0.3f) ? 1.0f : 0.0f;
                bhi |= (u64)(m > 0.3f) << tt;
            }
            cm = m; cs = sp;
            if constexpr (WRITE_SPK) {       // coalesced bf16 spike store
                unsigned short* so = (unsigned short*)Sout + arow * N + nb + tid;
#pragma unroll 4
                for (int t = 0; t < 64; ++t)
                    so[(size_t)t * N] = ((blo >> t) & 1) ? 0x3F80 : 0;
                so += (size_t)64 * N;
#pragma unroll 4
                for (int t = 0; t < 64; ++t)
                    so[(size_t)t * N] = ((bhi >> t) & 1) ? 0x3F80 : 0;
            } else {
                if (s == T_ / TS_ - 1)
                    outp[(size_t)b * N + nb + tid] = cs;   // spike at t=511
            }
        }
    }
}

extern "C" void kernel_launch(void* const* d_in, const int* in_sizes, int n_in,
                              void* d_out, int out_size, void* d_ws, size_t ws_size,
                              hipStream_t stream)
{
    const float* x  = (const float*)d_in[0];
    const float* w0 = (const float*)d_in[1];
    const float* w1 = (const float*)d_in[2];
    const float* w2 = (const float*)d_in[3];
    float* out = (float*)d_out;

    char* p = (char*)d_ws;
    bf16* w0h = (bf16*)p;  p += (size_t)N1_ * D0_ * 2;
    bf16* w0l = (bf16*)p;  p += (size_t)N1_ * D0_ * 2;
    bf16* w1h = (bf16*)p;  p += (size_t)N2_ * N1_ * 2;
    bf16* w1l = (bf16*)p;  p += (size_t)N2_ * N1_ * 2;
    bf16* w2h = (bf16*)p;  p += (size_t)N3_ * N2_ * 2;
    bf16* w2l = (bf16*)p;  p += (size_t)N3_ * N2_ * 2;
    bf16* Xh   = (bf16*)p; p += (size_t)T_ * B_ * D0_ * 2;   // 67 MB
    bf16* Xl   = (bf16*)p; p += (size_t)T_ * B_ * D0_ * 2;   // 67 MB
    bf16* spk0 = (bf16*)p; p += (size_t)T_ * B_ * N1_ * 2;   // 134 MB
    bf16* spk1 = (bf16*)p; p += (size_t)T_ * B_ * N2_ * 2;   // 134 MB

    split_w<<<dim3(D0_/32, N1_/32), 256, 0, stream>>>(w0, w0h, w0l, D0_, N1_);
    split_w<<<dim3(N1_/32, N2_/32), 256, 0, stream>>>(w1, w1h, w1l, N1_, N2_);
    split_w<<<dim3(N2_/32, N3_/32), 256, 0, stream>>>(w2, w2h, w2l, N2_, N3_);
    split_x<<<dim3(D0_/32, T_/32, B_), 256, 0, stream>>>(x, Xh, Xl);

    // L0: all slices, X@w0 (3-term split) + LIF -> spk0 train
    snn_layer<D0_, true, true><<<dim3(B_, N1_/128), 256, 0, stream>>>(
        Xh, Xl, w0h, w0l, spk0, nullptr, N1_);
    // L1: all slices, spk0@w1 + LIF -> spk1 train
    snn_layer<N1_, false, true><<<dim3(B_, N2_/128), 256, 0, stream>>>(
        spk0, nullptr, w1h, w1l, spk1, nullptr, N2_);
    // L2: all slices, spk1@w2 + LIF -> final spikes to d_out
    snn_layer<N2_, false, false><<<dim3(B_, N3_/128), 256, 0, stream>>>(
        spk1, nullptr, w2h, w2l, nullptr, out, N3_);
}